// Round 1
// baseline (1745.427 us; speedup 1.0000x reference)
//
#include <hip/hip_runtime.h>
#include <hip/hip_bf16.h>

typedef __bf16 bf16_t;
typedef __bf16 bf16x8 __attribute__((ext_vector_type(8)));
typedef float f32x4 __attribute__((ext_vector_type(4)));

#define T_TOKENS 8192
#define DIM 1024
#define HID 2816
#define NE 8
#define H_ROWS 24576  // 16384 routed + 8192 shared

// async global->LDS, 16B per lane; LDS dest = uniform base + lane*16
#define GLDS(gp, lp)                                                              \
    __builtin_amdgcn_global_load_lds(                                             \
        (const __attribute__((address_space(1))) void*)(const void*)(gp),         \
        (__attribute__((address_space(3))) void*)(void*)(lp), 16, 0, 0)

#define VMW4 asm volatile("s_waitcnt vmcnt(4)" ::: "memory")
#define VMNOP ((void)0)

// ---- workspace layout (bytes) ----
static constexpr size_t H_OFF = 0;
static constexpr size_t H_BYTES = (size_t)H_ROWS * HID * 2;           // 138,412,032
static constexpr size_t CNT_OFF = H_OFF + H_BYTES;                    // int[8]
static constexpr size_t FILL_OFF = CNT_OFF + 32;                      // int[8]
static constexpr size_t OFFS_OFF = FILL_OFF + 32;                     // int[16]
static constexpr size_t TOPKI_OFF = OFFS_OFF + 64;                    // int[T][2]
static constexpr size_t TOPKW_OFF = TOPKI_OFF + (size_t)T_TOKENS * 2 * 4;
static constexpr size_t ROWMAP_OFF = TOPKW_OFF + (size_t)T_TOKENS * 2 * 4;
static constexpr size_t TOKROW_OFF = ROWMAP_OFF + (size_t)H_ROWS * 4; // int[T][2]
static constexpr size_t XB_OFF = (TOKROW_OFF + (size_t)T_TOKENS * 2 * 4 + 255) & ~(size_t)255;
static constexpr size_t XB_BYTES = (size_t)T_TOKENS * DIM * 2;        // 16.8 MB
static constexpr size_t W1B_OFF = XB_OFF + XB_BYTES;                  // 9 experts (8 routed + shared)
static constexpr size_t WEB_BYTES = (size_t)9 * HID * DIM * 2;        // 51.9 MB
static constexpr size_t W3B_OFF = W1B_OFF + WEB_BYTES;
static constexpr size_t W2B_OFF = W3B_OFF + WEB_BYTES;
// Y (fp32 partial outputs) overlays w1b/w3b: dead after gemm1.
static constexpr size_t Y_OFF = W1B_OFF;

// ---------------- fp32 -> bf16 conversion of x + all weights ----------------
struct CvtArgs {
    const float* s[7];
    bf16_t* d[7];
    int n8[7];
};

__global__ void convert_kernel(CvtArgs a)
{
    const int t = blockIdx.y;
    const float4* s = (const float4*)a.s[t];
    bf16x8* d = (bf16x8*)a.d[t];
    const int n8 = a.n8[t];
    for (int i = blockIdx.x * blockDim.x + threadIdx.x; i < n8; i += gridDim.x * blockDim.x) {
        float4 v0 = s[i * 2];
        float4 v1 = s[i * 2 + 1];
        bf16x8 b = {(bf16_t)v0.x, (bf16_t)v0.y, (bf16_t)v0.z, (bf16_t)v0.w,
                    (bf16_t)v1.x, (bf16_t)v1.y, (bf16_t)v1.z, (bf16_t)v1.w};
        d[i] = b;
    }
}

// ---------------- gating: one wave per token, fp64 dot to avoid top-k flips ----------------
__global__ void gate_kernel(const float* __restrict__ x, const float* __restrict__ gw,
                            int* __restrict__ topk_idx, float* __restrict__ topk_w,
                            int* __restrict__ counts)
{
    int tok = (blockIdx.x * blockDim.x + threadIdx.x) >> 6;
    int lane = threadIdx.x & 63;
    if (tok >= T_TOKENS) return;
    const float* xr = x + (size_t)tok * DIM;
    float xl[16];
#pragma unroll
    for (int i = 0; i < 16; i++) xl[i] = xr[lane + 64 * i];
    double lg[NE];
#pragma unroll
    for (int e = 0; e < NE; e++) {
        const float* g = gw + e * DIM;
        double s = 0.0;
#pragma unroll
        for (int i = 0; i < 16; i++) s += (double)xl[i] * (double)g[lane + 64 * i];
#pragma unroll
        for (int off = 32; off > 0; off >>= 1) s += __shfl_xor(s, off, 64);
        lg[e] = s;
    }
    if (lane == 0) {
        double mx = lg[0];
        for (int e = 1; e < NE; e++) mx = lg[e] > mx ? lg[e] : mx;
        double sum = 0.0, sc[NE];
        for (int e = 0; e < NE; e++) { sc[e] = exp(lg[e] - mx); sum += sc[e]; }
        for (int e = 0; e < NE; e++) sc[e] /= sum;
        int i0 = 0;
        for (int e = 1; e < NE; e++) if (sc[e] > sc[i0]) i0 = e;  // strict > : first occurrence wins
        int i1 = -1;
        for (int e = 0; e < NE; e++) { if (e == i0) continue; if (i1 < 0 || sc[e] > sc[i1]) i1 = e; }
        double s0 = sc[i0], s1 = sc[i1];
        double inv = 1.0 / (s0 + s1 + 1e-20);
        topk_idx[tok * 2 + 0] = i0;
        topk_idx[tok * 2 + 1] = i1;
        topk_w[tok * 2 + 0] = (float)(s0 * inv);
        topk_w[tok * 2 + 1] = (float)(s1 * inv);
        atomicAdd(&counts[i0], 1);
        atomicAdd(&counts[i1], 1);
    }
}

__global__ void offsets_kernel(const int* __restrict__ counts, int* __restrict__ offsets)
{
    if (threadIdx.x == 0) {
        int acc = 0;
        for (int e = 0; e < NE; e++) { offsets[e] = acc; acc += counts[e]; }
        offsets[8] = 16384;  // shared group base
        offsets[9] = H_ROWS;
    }
}

__global__ void scatter_kernel(const int* __restrict__ topk_idx,
                               const int* __restrict__ offsets, int* __restrict__ fill,
                               int* __restrict__ rowmap, int* __restrict__ tokrow)
{
    int t = blockIdx.x * blockDim.x + threadIdx.x;
    if (t >= T_TOKENS) return;
#pragma unroll
    for (int k = 0; k < 2; k++) {
        int e = topk_idx[t * 2 + k];
        int slot = atomicAdd(&fill[e], 1);
        int r = offsets[e] + slot;
        rowmap[r] = t;
        tokrow[t * 2 + k] = r;
    }
    rowmap[16384 + t] = t;   // shared expert identity map
}

// ---------------- GEMM1: H = silu(x.w1^T) * (x.w3^T) ----------------
// 8-phase 256x128 dual-B schedule: 512 thr (8 waves, 2M x 4N), BK=64,
// LDS = A(64K) + B1(32K) + B3(32K) = 128 KB, counted vmcnt, setprio.
// LDS layout per tensor buf: 16B units, data (row,c) at unit row*8 + (c ^ ((row>>1)&7))
__global__ __launch_bounds__(512, 2)
void gemm1_kernel(const bf16_t* __restrict__ xb,
                  const bf16_t* __restrict__ w1b, const bf16_t* __restrict__ w3b,
                  const int* __restrict__ offsets, const int* __restrict__ counts,
                  const int* __restrict__ rowmap, bf16_t* __restrict__ Hout)
{
    constexpr int NWG = 22 * 288;
    const int bid = blockIdx.x;
    // bijective XCD-chunk swizzle (NWG % 8 == 0): each XCD gets contiguous wids,
    // nt fastest -> same A-panel resident in the XCD's L2 across its 22 N-tiles
    const int wid = (bid & 7) * (NWG >> 3) + (bid >> 3);
    const int nt = wid % 22;
    const int myt = wid / 22;
    const int g = myt >> 5, mtile = myt & 31;
    const int cnt = (g < NE) ? counts[g] : T_TOKENS;
    const int mbase = mtile * 256;
    if (mbase >= cnt) return;
    const int nbase = nt * 128;
    const int rowoff = offsets[g];
    const bf16_t* B1 = w1b + (size_t)g * HID * DIM;
    const bf16_t* B3 = w3b + (size_t)g * HID * DIM;

    __shared__ bf16_t sA[2][256 * 64];
    __shared__ bf16_t sB1[2][128 * 64];
    __shared__ bf16_t sB3[2][128 * 64];

    const int tid = threadIdx.x, wave = tid >> 6, lane = tid & 63;

    // staging source pointers (pre-swizzled global col so LDS stays linear)
    const bf16_t* srcA[4];
    const bf16_t* srcB1[2];
    const bf16_t* srcB3[2];
#pragma unroll
    for (int o = 0; o < 4; o++) {
        const int U = o * 512 + tid;
        const int row = U >> 3;
        const int c = (U & 7) ^ ((row >> 1) & 7);
        const int tok = rowmap[rowoff + mbase + row];
        srcA[o] = xb + (size_t)tok * DIM + c * 8;
    }
#pragma unroll
    for (int o = 0; o < 2; o++) {
        const int U = o * 512 + tid;
        const int row = U >> 3;
        const int c = (U & 7) ^ ((row >> 1) & 7);
        srcB1[o] = B1 + (size_t)(nbase + row) * DIM + c * 8;
        srcB3[o] = B3 + (size_t)(nbase + row) * DIM + c * 8;
    }

#define G1_STAGE_A(bi, h, t) do {                                               \
    GLDS(srcA[(h)*2+0] + (t)*64, &sA[bi][(((h)*2+0)*512 + wave*64)*8]);         \
    GLDS(srcA[(h)*2+1] + (t)*64, &sA[bi][(((h)*2+1)*512 + wave*64)*8]); } while (0)
#define G1_STAGE_B1(bi, t) do {                                                 \
    GLDS(srcB1[0] + (t)*64, &sB1[bi][(wave*64)*8]);                             \
    GLDS(srcB1[1] + (t)*64, &sB1[bi][(512 + wave*64)*8]); } while (0)
#define G1_STAGE_B3(bi, t) do {                                                 \
    GLDS(srcB3[0] + (t)*64, &sB3[bi][(wave*64)*8]);                             \
    GLDS(srcB3[1] + (t)*64, &sB3[bi][(512 + wave*64)*8]); } while (0)

    const int wm = wave >> 2, wn = wave & 3;   // 2M x 4N waves; per-wave 128x32
    const int fm = lane & 15, fq = lane >> 4;
    const int swz = (fm >> 1) & 7;
    int ab[2], bb[2];
#pragma unroll
    for (int s = 0; s < 2; s++) {
        ab[s] = (wm * 128 + fm) * 64 + (((s * 4 + fq) ^ swz) * 8);
        bb[s] = (wn * 32 + fm) * 64 + (((s * 4 + fq) ^ swz) * 8);
    }

    const f32x4 zero = {0.f, 0.f, 0.f, 0.f};
    f32x4 acc1[8][2], acc2[8][2];
#pragma unroll
    for (int m = 0; m < 8; m++)
#pragma unroll
        for (int j = 0; j < 2; j++) { acc1[m][j] = zero; acc2[m][j] = zero; }
    bf16x8 bfr1[2][2], bfr3[2][2], af[2][2];

    // prologue: tile0 (B1,B3,A) -> buf0 ; tile1 (B1,B3) -> buf1 ; 12 loads
    G1_STAGE_B1(0, 0); G1_STAGE_B3(0, 0);
    G1_STAGE_A(0, 0, 0); G1_STAGE_A(0, 1, 0);
    G1_STAGE_B1(1, 1); G1_STAGE_B3(1, 1);
    VMW4;  // tile0 fully landed; tile1 B in flight
    __builtin_amdgcn_s_barrier();

#define G1_PHASE(bi, q, STAGE_STMT, VM_STMT) {                                   \
    if ((q) == 0) {                                                              \
        _Pragma("unroll") for (int j = 0; j < 2; j++)                            \
        _Pragma("unroll") for (int s = 0; s < 2; s++) {                          \
            bfr1[j][s] = *(const bf16x8*)&sB1[bi][bb[s] + j * 1024];             \
            bfr3[j][s] = *(const bf16x8*)&sB3[bi][bb[s] + j * 1024];             \
        }                                                                        \
    }                                                                            \
    _Pragma("unroll") for (int mi = 0; mi < 2; mi++)                             \
    _Pragma("unroll") for (int s = 0; s < 2; s++)                                \
        af[mi][s] = *(const bf16x8*)&sA[bi][ab[s] + ((q) * 2 + mi) * 1024];      \
    STAGE_STMT;                                                                  \
    VM_STMT;                                                                     \
    asm volatile("s_waitcnt lgkmcnt(0)" ::: "memory");                           \
    __builtin_amdgcn_s_barrier();                                                \
    __builtin_amdgcn_sched_barrier(0);                                           \
    __builtin_amdgcn_s_setprio(1);                                               \
    _Pragma("unroll") for (int mi = 0; mi < 2; mi++)                             \
    _Pragma("unroll") for (int j = 0; j < 2; j++)                                \
    _Pragma("unroll") for (int s = 0; s < 2; s++) {                              \
        acc1[(q)*2+mi][j] = __builtin_amdgcn_mfma_f32_16x16x32_bf16(             \
            af[mi][s], bfr1[j][s], acc1[(q)*2+mi][j], 0, 0, 0);                  \
        acc2[(q)*2+mi][j] = __builtin_amdgcn_mfma_f32_16x16x32_bf16(             \
            af[mi][s], bfr3[j][s], acc2[(q)*2+mi][j], 0, 0, 0);                  \
    }                                                                            \
    __builtin_amdgcn_s_setprio(0);                                               \
    __builtin_amdgcn_s_barrier();                                                \
}

    // steady-state stage map: p1/p2: O.A -> buf1 ; p3/p4: E'.B -> buf0 ;
    // p5/p6: E'.A -> buf0 ; p7/p8: O'.B -> buf1 ; vmcnt(4) at p4/p8 only.
    for (int it = 0; it < 8; ++it) {                 // nk = 16, 2 tiles/iter
        const int O = 2 * it + 1;
        const int En = (2 * it + 2 < 16) ? 2 * it + 2 : 2 * it;   // clamped (dead slot)
        const int On = (O + 2 < 16) ? O + 2 : O;
        G1_PHASE(0, 0, G1_STAGE_A(1, 0, O), VMNOP);
        G1_PHASE(0, 1, G1_STAGE_A(1, 1, O), VMNOP);
        G1_PHASE(0, 2, G1_STAGE_B1(0, En), VMNOP);
        G1_PHASE(0, 3, G1_STAGE_B3(0, En), VMW4);
        G1_PHASE(1, 0, G1_STAGE_A(0, 0, En), VMNOP);
        G1_PHASE(1, 1, G1_STAGE_A(0, 1, En), VMNOP);
        G1_PHASE(1, 2, G1_STAGE_B1(1, On), VMNOP);
        G1_PHASE(1, 3, G1_STAGE_B3(1, On), VMW4);
    }
#undef G1_PHASE

    // epilogue: h = silu(p1)*p2, non-temporal bf16 store into packed H
    const size_t hbase = (size_t)(rowoff + mbase);
#pragma unroll
    for (int m = 0; m < 8; m++) {
#pragma unroll
        for (int r = 0; r < 4; r++) {
            const int lr = wm * 128 + m * 16 + fq * 4 + r;
            if (mbase + lr < cnt) {
                bf16_t* hp = Hout + (hbase + lr) * (size_t)HID + nbase + wn * 32;
#pragma unroll
                for (int j = 0; j < 2; j++) {
                    const float v1 = acc1[m][j][r];
                    const float v2 = acc2[m][j][r];
                    const float h = (v1 / (1.f + __expf(-v1))) * v2;
                    const bf16_t hv = (bf16_t)h;
                    short hs;
                    __builtin_memcpy(&hs, &hv, 2);
                    __builtin_nontemporal_store(hs, (short*)(hp + j * 16 + fm));
                }
            }
        }
    }
#undef G1_STAGE_A
#undef G1_STAGE_B1
#undef G1_STAGE_B3
}

// ---------------- GEMM2: Y[row, d] = H[row] . w2[g]^T (unweighted partials) ----------------
// 8-phase 256x256: 512 thr (8 waves, 2M x 4N), BK=64, LDS = 128 KB.
__global__ __launch_bounds__(512, 2)
void gemm2_kernel(const bf16_t* __restrict__ Hin, const bf16_t* __restrict__ w2b,
                  const int* __restrict__ offsets, const int* __restrict__ counts,
                  float* __restrict__ Y)
{
    constexpr int NWG = 4 * 288;
    const int bid = blockIdx.x;
    const int wid = (bid & 7) * (NWG >> 3) + (bid >> 3);
    const int nt = wid & 3;
    const int myt = wid >> 2;
    const int g = myt >> 5, mtile = myt & 31;
    const int cnt = (g < NE) ? counts[g] : T_TOKENS;
    const int mbase = mtile * 256;
    if (mbase >= cnt) return;
    const int nbase = nt * 256;
    const int rowoff = offsets[g];
    const bf16_t* B = w2b + (size_t)g * DIM * HID;
    const size_t habase = (size_t)(rowoff + mbase);

    __shared__ bf16_t sA[2][256 * 64];
    __shared__ bf16_t sB[2][256 * 64];

    const int tid = threadIdx.x, wave = tid >> 6, lane = tid & 63;

    const bf16_t* srcA[4];
    const bf16_t* srcB[4];
#pragma unroll
    for (int o = 0; o < 4; o++) {
        const int U = o * 512 + tid;
        const int row = U >> 3;
        const int c = (U & 7) ^ ((row >> 1) & 7);
        srcA[o] = Hin + (habase + row) * (size_t)HID + c * 8;
        srcB[o] = B + (size_t)(nbase + row) * HID + c * 8;
    }

#define G2_STAGE_A(bi, h, t) do {                                               \
    GLDS(srcA[(h)*2+0] + (t)*64, &sA[bi][(((h)*2+0)*512 + wave*64)*8]);         \
    GLDS(srcA[(h)*2+1] + (t)*64, &sA[bi][(((h)*2+1)*512 + wave*64)*8]); } while (0)
#define G2_STAGE_B(bi, h, t) do {                                               \
    GLDS(srcB[(h)*2+0] + (t)*64, &sB[bi][(((h)*2+0)*512 + wave*64)*8]);         \
    GLDS(srcB[(h)*2+1] + (t)*64, &sB[bi][(((h)*2+1)*512 + wave*64)*8]); } while (0)

    const int wm = wave >> 2, wn = wave & 3;   // per-wave 128 x 64
    const int fm = lane & 15, fq = lane >> 4;
    const int swz = (fm >> 1) & 7;
    int ab[2], bb[2];
#pragma unroll
    for (int s = 0; s < 2; s++) {
        ab[s] = (wm * 128 + fm) * 64 + (((s * 4 + fq) ^ swz) * 8);
        bb[s] = (wn * 64 + fm) * 64 + (((s * 4 + fq) ^ swz) * 8);
    }

    const f32x4 zero = {0.f, 0.f, 0.f, 0.f};
    f32x4 acc[8][4];
#pragma unroll
    for (int m = 0; m < 8; m++)
#pragma unroll
        for (int n = 0; n < 4; n++) acc[m][n] = zero;
    bf16x8 bfr[4][2], af[2][2];

    G2_STAGE_B(0, 0, 0); G2_STAGE_B(0, 1, 0);
    G2_STAGE_A(0, 0, 0); G2_STAGE_A(0, 1, 0);
    G2_STAGE_B(1, 0, 1); G2_STAGE_B(1, 1, 1);
    VMW4;
    __builtin_amdgcn_s_barrier();

#define G2_PHASE(bi, q, STAGE_STMT, VM_STMT) {                                   \
    if ((q) == 0) {                                                              \
        _Pragma("unroll") for (int n = 0; n < 4; n++)                            \
        _Pragma("unroll") for (int s = 0; s < 2; s++)                            \
            bfr[n][s] = *(const bf16x8*)&sB[bi][bb[s] + n * 1024];               \
    }                                                                            \
    _Pragma("unroll") for (int mi = 0; mi < 2; mi++)                             \
    _Pragma("unroll") for (int s = 0; s < 2; s++)                                \
        af[mi][s] = *(const bf16x8*)&sA[bi][ab[s] + ((q) * 2 + mi) * 1024];      \
    STAGE_STMT;                                                                  \
    VM_STMT;                                                                     \
    asm volatile("s_waitcnt lgkmcnt(0)" ::: "memory");                           \
    __builtin_amdgcn_s_barrier();                                                \
    __builtin_amdgcn_sched_barrier(0);                                           \
    __builtin_amdgcn_s_setprio(1);                                               \
    _Pragma("unroll") for (int mi = 0; mi < 2; mi++)                             \
    _Pragma("unroll") for (int n = 0; n < 4; n++)                                \
    _Pragma("unroll") for (int s = 0; s < 2; s++)                                \
        acc[(q)*2+mi][n] = __builtin_amdgcn_mfma_f32_16x16x32_bf16(              \
            af[mi][s], bfr[n][s], acc[(q)*2+mi][n], 0, 0, 0);                    \
    __builtin_amdgcn_s_setprio(0);                                               \
    __builtin_amdgcn_s_barrier();                                                \
}

    for (int it = 0; it < 22; ++it) {               // nk = 44
        const int O = 2 * it + 1;
        const int En = (2 * it + 2 < 44) ? 2 * it + 2 : 2 * it;
        const int On = (O + 2 < 44) ? O + 2 : O;
        G2_PHASE(0, 0, G2_STAGE_A(1, 0, O), VMNOP);
        G2_PHASE(0, 1, G2_STAGE_A(1, 1, O), VMNOP);
        G2_PHASE(0, 2, G2_STAGE_B(0, 0, En), VMNOP);
        G2_PHASE(0, 3, G2_STAGE_B(0, 1, En), VMW4);
        G2_PHASE(1, 0, G2_STAGE_A(0, 0, En), VMNOP);
        G2_PHASE(1, 1, G2_STAGE_A(0, 1, En), VMNOP);
        G2_PHASE(1, 2, G2_STAGE_B(1, 0, On), VMNOP);
        G2_PHASE(1, 3, G2_STAGE_B(1, 1, On), VMW4);
    }
#undef G2_PHASE

#pragma unroll
    for (int m = 0; m < 8; m++) {
#pragma unroll
        for (int r = 0; r < 4; r++) {
            const int lr = wm * 128 + m * 16 + fq * 4 + r;
            if (mbase + lr < cnt) {
                float* yp = Y + (size_t)(rowoff + mbase + lr) * DIM + nbase + wn * 64;
#pragma unroll
                for (int n = 0; n < 4; n++)
                    __builtin_nontemporal_store(acc[m][n][r], yp + n * 16 + fm);
            }
        }
    }
#undef G2_STAGE_A
#undef G2_STAGE_B
}

// ---------------- combine: out[t] = w0*Y[r0] + w1*Y[r1] + Y[16384+t] ----------------
__global__ void combine_kernel(const float* __restrict__ Y, const int* __restrict__ tokrow,
                               const float* __restrict__ tkw, float* __restrict__ out)
{
    const int t = blockIdx.x;
    const int d = threadIdx.x;              // 256 threads, one float4 each
    const int r0 = tokrow[t * 2 + 0];
    const int r1 = tokrow[t * 2 + 1];
    const float w0 = tkw[t * 2 + 0];
    const float w1 = tkw[t * 2 + 1];
    const float4 a = ((const float4*)(Y + (size_t)r0 * DIM))[d];
    const float4 b = ((const float4*)(Y + (size_t)r1 * DIM))[d];
    const float4 c = ((const float4*)(Y + (size_t)(16384 + t) * DIM))[d];
    float4 o;
    o.x = w0 * a.x + w1 * b.x + c.x;
    o.y = w0 * a.y + w1 * b.y + c.y;
    o.z = w0 * a.z + w1 * b.z + c.z;
    o.w = w0 * a.w + w1 * b.w + c.w;
    ((float4*)(out + (size_t)t * DIM))[d] = o;
}

extern "C" void kernel_launch(void* const* d_in, const int* in_sizes, int n_in,
                              void* d_out, int out_size, void* d_ws, size_t ws_size,
                              hipStream_t stream)
{
    const float* x   = (const float*)d_in[0];
    const float* gw  = (const float*)d_in[1];
    const float* w1  = (const float*)d_in[2];
    const float* w2  = (const float*)d_in[3];
    const float* w3  = (const float*)d_in[4];
    const float* sw1 = (const float*)d_in[5];
    const float* sw2 = (const float*)d_in[6];
    const float* sw3 = (const float*)d_in[7];
    float* out = (float*)d_out;
    char* ws = (char*)d_ws;

    bf16_t* H    = (bf16_t*)(ws + H_OFF);
    int* counts  = (int*)(ws + CNT_OFF);
    int* fill    = (int*)(ws + FILL_OFF);
    int* offs    = (int*)(ws + OFFS_OFF);
    int* tki     = (int*)(ws + TOPKI_OFF);
    float* tkw   = (float*)(ws + TOPKW_OFF);
    int* rowmap  = (int*)(ws + ROWMAP_OFF);
    int* tokrow  = (int*)(ws + TOKROW_OFF);
    bf16_t* xb   = (bf16_t*)(ws + XB_OFF);
    bf16_t* w1b  = (bf16_t*)(ws + W1B_OFF);
    bf16_t* w3b  = (bf16_t*)(ws + W3B_OFF);
    bf16_t* w2b  = (bf16_t*)(ws + W2B_OFF);
    float* Y     = (float*)(ws + Y_OFF);   // overlays w1b/w3b (dead after gemm1)

    (void)in_sizes; (void)n_in; (void)out_size; (void)ws_size;

    hipMemsetAsync(ws + CNT_OFF, 0, 64, stream);  // counts + fill

    CvtArgs ca;
    ca.s[0] = x;   ca.d[0] = xb;                           ca.n8[0] = T_TOKENS * DIM / 8;
    ca.s[1] = w1;  ca.d[1] = w1b;                          ca.n8[1] = NE * HID * DIM / 8;
    ca.s[2] = sw1; ca.d[2] = w1b + (size_t)NE * HID * DIM; ca.n8[2] = HID * DIM / 8;
    ca.s[3] = w3;  ca.d[3] = w3b;                          ca.n8[3] = NE * HID * DIM / 8;
    ca.s[4] = sw3; ca.d[4] = w3b + (size_t)NE * HID * DIM; ca.n8[4] = HID * DIM / 8;
    ca.s[5] = w2;  ca.d[5] = w2b;                          ca.n8[5] = NE * DIM * HID / 8;
    ca.s[6] = sw2; ca.d[6] = w2b + (size_t)NE * DIM * HID; ca.n8[6] = DIM * HID / 8;
    convert_kernel<<<dim3(1024, 7), 256, 0, stream>>>(ca);

    gate_kernel<<<T_TOKENS / 4, 256, 0, stream>>>(x, gw, tki, tkw, counts);
    offsets_kernel<<<1, 64, 0, stream>>>(counts, offs);
    scatter_kernel<<<T_TOKENS / 256, 256, 0, stream>>>(tki, offs, fill, rowmap, tokrow);
    gemm1_kernel<<<dim3(22 * 288), 512, 0, stream>>>(xb, w1b, w3b, offs, counts, rowmap, H);
    gemm2_kernel<<<dim3(4 * 288), 512, 0, stream>>>(H, w2b, offs, counts, Y);
    combine_kernel<<<T_TOKENS, 256, 0, stream>>>(Y, tokrow, tkw, out);
}